// Round 15
// baseline (77.173 us; speedup 1.0000x reference)
//
#include <hip/hip_runtime.h>
#include <math.h>

// RWKV-6 fused recurrent WKV — chunked linear scan, MFMA formulation.
// B=4, T=2048, H=16, N=64, fp32 in/out; bf16 MFMA operands, fp32 accum.
//
// Chunk TC=64 per workgroup (bh,g), 4 waves, wave w owns t-band [16w,16w+16).
// A[t,s] = sum_i r_t,i k_s,i exp(-(c[t-1]-c[s])), c = incl. prefix of exp(w).
// Dyadic-safe factorization (all staged exponents <= 0). Levels 0-3 + u-diag
// inside 16x16 diag tiles (masked accum); L4: tiles (1,0),(3,2); L5: (2,*),
// (3,0),(3,1). o = R~0 @ S0 + A @ V;  L_g = K~end^T @ V -> K2 scan.
//
// R8 lesson: never trade register live-range for LDS (accO stays last).
// R9 lesson: __float2bfloat16 tips regalloc into spill; manual RNE is stable.
// R10 lesson: phase-1 wall is the CU-shared LDS pipe (staging writes).
// R11-R14 lessons (NaN x4): (a) sST staging copied only 8 of 16 columns
//   (uint4 = 8 bf16) -> uninitialized LDS into the R~0@S0 MFMA. Fixed below
//   with TWO 16B copies. (b) R12/R14's union{s8v,u[4]} punning packed
//   stagings are the remaining unexonerated construct -> EXCLUDED here.
//   R15 = R13 verbatim + the sST fix: zero unions, zero cvtpk, zero DPP;
//   every primitive is R10-proven.
// Kept delta vs R10: L/S0 stored bf16 TRANSPOSED [j][i] per chunk
//   (k2 traffic 67.5->34MB, P0 L-write halves, P1 sST = pure bit-copies).

namespace {
constexpr int B = 4, T = 2048, H = 16, N = 64;
constexpr int BH = B * H;
constexpr int NG = 32;           // chunks per (b,h)
constexpr int TC = 64;           // steps per chunk
constexpr int LDP = 72;          // LDS row stride (elems): 144B, 16B-aligned

typedef __attribute__((ext_vector_type(8))) short s8v;   // 8 bf16
typedef __attribute__((ext_vector_type(4))) float f4v;

#define MFMA16(a, b, c) __builtin_amdgcn_mfma_f32_16x16x32_bf16((a), (b), (c), 0, 0, 0)

__device__ __forceinline__ unsigned short cv(float f) {
    union { float f; unsigned u; } x; x.f = f;
    unsigned r = x.u + 0x7FFFu + ((x.u >> 16) & 1u);   // branchless RNE
    return (unsigned short)(r >> 16);
}

__device__ __forceinline__ float bfhi(unsigned u) {   // upper bf16 -> float
    union { unsigned u; float f; } x; x.u = u & 0xFFFF0000u; return x.f;
}
__device__ __forceinline__ float bflo(unsigned u) {   // lower bf16 -> float
    union { unsigned u; float f; } x; x.u = u << 16; return x.f;
}

// Padded element index: row*72 + col. Affine in row (no xor recompute).
__device__ __forceinline__ int sw(int row, int col) {
    return row * LDP + col;
}

// MFMA fragment load: lane l -> row (l&15), k-slice 8*(l>>4); b128 read.
__device__ __forceinline__ s8v frag8(const unsigned short* buf, int row_base, int k_base) {
    const int l = threadIdx.x & 63;
    return *(const s8v*)&buf[sw(row_base + (l & 15), k_base + 8 * (l >> 4))];
}

// ---------------- K1/K3 merged: PHASE 0 = local states, PHASE 1 = outputs ---
// Lg/S0g: bf16, TRANSPOSED per chunk: [j][i] (j-major, 64x64).
template<int PHASE>
__global__ __launch_bounds__(256, 4)
void k13(const float* __restrict__ rp, const float* __restrict__ kp,
         const float* __restrict__ vp, const float* __restrict__ wp,
         const float* __restrict__ up,
         const unsigned short* __restrict__ S0g,   // PHASE1: chunk-start states
         unsigned short* __restrict__ Lg, float* __restrict__ Ag,
         float* __restrict__ out)
{
    __shared__ unsigned short sA[64 * LDP];   // staging A-op; aliases sAm (late)
    __shared__ unsigned short sB[64 * LDP];   // staging B-op
    __shared__ unsigned short sVT[64 * LDP];  // V transposed [j][t]
    __shared__ unsigned short sST[64 * LDP];  // S0 [j][i] (PHASE1)
    __shared__ float spans[4 * 64];
    unsigned short* const sAm = sA;           // A-matrix bf16 [t][s] (late alias)

    const int blk = blockIdx.x;
    const int g   = blk & (NG - 1);
    const int bh  = blk / NG;
    const int b   = bh / H, h = bh - b * H;
    const int wv  = threadIdx.x >> 6;        // wave 0..3, owns t-band [16wv,+16)
    const int ln  = threadIdx.x & 63;        // lane: i (prep) / frag lane (GEMM)

    const int stride = H * N;
    const int base_w = ((b * T + g * TC + wv * 16) * H + h) * N + ln;
    const int cb = (bh * NG + g) * (N * N);

    // ---- P1: load rows, cum prefix, stage V^T (and S0) ---------------------
    float ci[16];                            // inclusive prefix of exp(w)
    float k_[16], r_[16];
    {
        float run = 0.f;
#pragma unroll
        for (int tt = 0; tt < 16; ++tt) {
            const int a = base_w + tt * stride;
            run += __expf(wp[a]);
            ci[tt] = run;
            k_[tt] = kp[a];
            if (PHASE == 1) r_[tt] = rp[a];
        }
        spans[wv * 64 + ln] = run;
    }
#pragma unroll
    for (int half = 0; half < 2; ++half) {   // V^T: row j=ln, cols t (own band)
        s8v pk;
#pragma unroll
        for (int e = 0; e < 8; ++e)
            pk[e] = (short)cv(vp[base_w + (half * 8 + e) * stride]);
        *(s8v*)&sVT[sw(ln, wv * 16 + half * 8)] = pk;
    }
    if (PHASE == 1) {
        // S0 [j][i]: pure bf16 bit-copy. 16 columns = TWO 16B copies (8 bf16
        // each). R11-R14 NaN root cause #1: a single 16B copy staged only
        // cols 0-7, leaving cols 8-15 uninitialized LDS.
        *(s8v*)&sST[sw(ln, wv * 16)] =
            *(const s8v*)&S0g[cb + ln * 64 + wv * 16];
        *(s8v*)&sST[sw(ln, wv * 16 + 8)] =
            *(const s8v*)&S0g[cb + ln * 64 + wv * 16 + 8];
    }
    __syncthreads();
    const float sp0 = spans[0 * 64 + ln], sp1 = spans[1 * 64 + ln];
    const float sp2 = spans[2 * 64 + ln], sp3 = spans[3 * 64 + ln];
    const float offW = (wv > 0 ? sp0 : 0.f) + (wv > 1 ? sp1 : 0.f) + (wv > 2 ? sp2 : 0.f);
    const float ctot = sp0 + sp1 + sp2 + sp3;

    if (PHASE == 0) {
        // ---- K~end^T staging into sA as [i=ln][t] --------------------------
        s8v p0, p1;
#pragma unroll
        for (int tt = 0; tt < 16; ++tt) {
            const unsigned short v16 =
                cv(k_[tt] * __expf(-(ctot - (offW + ci[tt]))));
            if (tt < 8) p0[tt] = (short)v16; else p1[tt - 8] = (short)v16;
        }
        *(s8v*)&sA[sw(ln, wv * 16)]     = p0;
        *(s8v*)&sA[sw(ln, wv * 16 + 8)] = p1;
        __syncthreads();
        // ---- L[j][i] = sum_t V[t][j] KT[i][t]; wave owns i-band ------------
#pragma unroll
        for (int jb = 0; jb < 4; ++jb) {
            f4v acc = {0.f, 0.f, 0.f, 0.f};
            acc = MFMA16(frag8(sA, wv * 16, 0),  frag8(sVT, jb * 16, 0),  acc);
            acc = MFMA16(frag8(sA, wv * 16, 32), frag8(sVT, jb * 16, 32), acc);
            // acc[q] at (i = wv*16+(ln>>4)*4+q, j = jb*16+(ln&15)); transposed
            // bf16 store: 4 consecutive i at row j -> one b64 write
            const int i0 = wv * 16 + (ln >> 4) * 4;
            const int j  = jb * 16 + (ln & 15);
            uint2 wsto;
            wsto.x = (unsigned)cv(acc[0]) | ((unsigned)cv(acc[1]) << 16);
            wsto.y = (unsigned)cv(acc[2]) | ((unsigned)cv(acc[3]) << 16);
            *(uint2*)&Lg[cb + j * 64 + i0] = wsto;
        }
        if (wv == 0) Ag[(bh * NG + g) * 64 + ln] = __expf(-ctot);
        return;
    }

    // ======================= PHASE 1: outputs ==============================
    const float uln = up[h * 64 + ln];
    const int cc = ln & 15;

    // ---- diag tile (wv,wv): shared plain-k B; level 0 + u-diag + levels 1-3
    f4v accD = {0.f, 0.f, 0.f, 0.f};
#pragma unroll
    for (int tt = 0; tt < 16; ++tt) sB[sw(wv * 16 + tt, ln)] = cv(k_[tt]);
    // level 0: scales identically 1 -> A = plain r
#pragma unroll
    for (int tt = 0; tt < 16; ++tt) sA[sw(wv * 16 + tt, ln)] = cv(r_[tt]);
    {
        f4v tmp = {0.f, 0.f, 0.f, 0.f};
        tmp = MFMA16(frag8(sA, wv * 16, 0),  frag8(sB, wv * 16, 0),  tmp);
        tmp = MFMA16(frag8(sA, wv * 16, 32), frag8(sB, wv * 16, 32), tmp);
#pragma unroll
        for (int q = 0; q < 4; ++q) {
            const int tt = (ln >> 4) * 4 + q;
            if (tt == cc + 1 && (tt & 1)) accD[q] += tmp[q];
        }
    }
    // u-diag: A = r*u, same plain-k B; mask t==s
#pragma unroll
    for (int tt = 0; tt < 16; ++tt) sA[sw(wv * 16 + tt, ln)] = cv(r_[tt] * uln);
    {
        f4v tmp = {0.f, 0.f, 0.f, 0.f};
        tmp = MFMA16(frag8(sA, wv * 16, 0),  frag8(sB, wv * 16, 0),  tmp);
        tmp = MFMA16(frag8(sA, wv * 16, 32), frag8(sB, wv * 16, 32), tmp);
#pragma unroll
        for (int q = 0; q < 4; ++q) {
            const int tt = (ln >> 4) * 4 + q;
            if (tt == cc) accD[q] += tmp[q];
        }
    }
    // levels 1..3: masked dyadic pairs
#pragma unroll
    for (int L = 1; L < 4; ++L) {
#pragma unroll
        for (int tt = 0; tt < 16; ++tt) {
            const int btl = (tt >> L) << L;          // floor boundary (local)
            const int bsl = btl + (1 << L);          // ceil boundary (local)
            const float cT  = (tt == 0) ? 0.f : ci[tt - 1];
            const float cBt = (btl == 0) ? 0.f : ci[btl - 1];
            const float cBs = ci[bsl - 1];
            sA[sw(wv * 16 + tt, ln)] = cv(r_[tt] * __expf(-(cT - cBt)));
            sB[sw(wv * 16 + tt, ln)] = cv(k_[tt] * __expf(-(cBs - ci[tt])));
        }
        f4v tmp = {0.f, 0.f, 0.f, 0.f};
        tmp = MFMA16(frag8(sA, wv * 16, 0),  frag8(sB, wv * 16, 0),  tmp);
        tmp = MFMA16(frag8(sA, wv * 16, 32), frag8(sB, wv * 16, 32), tmp);
#pragma unroll
        for (int q = 0; q < 4; ++q) {
            const int tt = (ln >> 4) * 4 + q;
            if (((tt >> L) == ((cc >> L) + 1)) && (((tt >> L) & 1) != 0))
                accD[q] += tmp[q];
        }
    }

    // ---- level 4: whole tiles (1,0),(3,2); refs = own band start/end -------
#pragma unroll
    for (int tt = 0; tt < 16; ++tt) {
        const float cT = (tt == 0) ? 0.f : ci[tt - 1];
        sA[sw(wv * 16 + tt, ln)] = cv(r_[tt] * __expf(-cT));
        sB[sw(wv * 16 + tt, ln)] = cv(k_[tt] * __expf(-(ci[15] - ci[tt])));
    }
    __syncthreads();
    f4v accL4 = {0.f, 0.f, 0.f, 0.f};
    if (wv == 1 || wv == 3) {
        accL4 = MFMA16(frag8(sA, wv * 16, 0),  frag8(sB, (wv - 1) * 16, 0),  accL4);
        accL4 = MFMA16(frag8(sA, wv * 16, 32), frag8(sB, (wv - 1) * 16, 32), accL4);
    }
    __syncthreads();   // cross-band sB reads done before L5 prep overwrites

    // ---- level 5: tiles (2,0),(2,1),(3,0),(3,1); refs at c[32] -------------
#pragma unroll
    for (int tt = 0; tt < 16; ++tt) {
        if (wv >= 2) {
            const float cT = (tt == 0) ? 0.f : ci[tt - 1];
            const float d  = (wv == 2) ? cT : (cT + sp2);
            sA[sw(wv * 16 + tt, ln)] = cv(r_[tt] * __expf(-d));
        } else {
            const float d = (wv == 0) ? (sp0 + sp1 - ci[tt]) : (sp1 - ci[tt]);
            sB[sw(wv * 16 + tt, ln)] = cv(k_[tt] * __expf(-d));
        }
    }
    __syncthreads();
    f4v acc50 = {0.f, 0.f, 0.f, 0.f}, acc51 = {0.f, 0.f, 0.f, 0.f};
    if (wv >= 2) {
        acc50 = MFMA16(frag8(sA, wv * 16, 0),  frag8(sB, 0, 0),   acc50);
        acc50 = MFMA16(frag8(sA, wv * 16, 32), frag8(sB, 0, 32),  acc50);
        acc51 = MFMA16(frag8(sA, wv * 16, 0),  frag8(sB, 16, 0),  acc51);
        acc51 = MFMA16(frag8(sA, wv * 16, 32), frag8(sB, 16, 32), acc51);
    }
    // (no barrier: R~0 prep below writes only own sA rows; L5 GEMM read own
    //  sA rows in-order and sB bands 0/1, which are not rewritten)

    // ---- R~0 (chunk-start ref) + O_inter = R~0 @ S0 (accO short-lived!) ----
#pragma unroll
    for (int tt = 0; tt < 16; ++tt) {
        const float cT = (tt == 0) ? 0.f : ci[tt - 1];
        sA[sw(wv * 16 + tt, ln)] = cv(r_[tt] * __expf(-(offW + cT)));
    }
    f4v accO[4];
#pragma unroll
    for (int jb = 0; jb < 4; ++jb) {
        f4v a = {0.f, 0.f, 0.f, 0.f};
        a = MFMA16(frag8(sA, wv * 16, 0),  frag8(sST, jb * 16, 0),  a);
        a = MFMA16(frag8(sA, wv * 16, 32), frag8(sST, jb * 16, 32), a);
        accO[jb] = a;
    }

    // ---- materialize A into sAm (=sA alias): own-band rows only, after the
    //      last own-row sA read (accO GEMM, wave-in-order) -> safe -----------
#pragma unroll
    for (int q = 0; q < 4; ++q) {
        const int tt = (ln >> 4) * 4 + q;
        sAm[sw(wv * 16 + tt, wv * 16 + cc)] = cv(accD[q]);
    }
    if (wv == 1 || wv == 3) {
#pragma unroll
        for (int q = 0; q < 4; ++q) {
            const int tt = (ln >> 4) * 4 + q;
            sAm[sw(wv * 16 + tt, (wv - 1) * 16 + cc)] = cv(accL4[q]);
        }
    }
    if (wv >= 2) {
#pragma unroll
        for (int q = 0; q < 4; ++q) {
            const int tt = (ln >> 4) * 4 + q;
            sAm[sw(wv * 16 + tt, cc)]      = cv(acc50[q]);
            sAm[sw(wv * 16 + tt, 16 + cc)] = cv(acc51[q]);
        }
    }
    if (wv == 0 || wv == 2) {    // zero upper-adjacent tile for K32 pairing
#pragma unroll
        for (int q = 0; q < 4; ++q) {
            const int tt = (ln >> 4) * 4 + q;
            sAm[sw(wv * 16 + tt, (wv + 1) * 16 + cc)] = 0;
        }
    }

    // ---- out = accO + A @ V (A-op: own rows; B-op: sVT stable since P1) ----
#pragma unroll
    for (int jb = 0; jb < 4; ++jb) {
        f4v a = accO[jb];
        a = MFMA16(frag8(sAm, wv * 16, 0), frag8(sVT, jb * 16, 0), a);
        if (wv >= 2)
            a = MFMA16(frag8(sAm, wv * 16, 32), frag8(sVT, jb * 16, 32), a);
#pragma unroll
        for (int q = 0; q < 4; ++q) {
            const int t = g * TC + wv * 16 + (ln >> 4) * 4 + q;
            out[((b * T + t) * H + h) * N + jb * 16 + (ln & 15)] = a[q];
        }
    }
}

// ---------------- K2: inter-chunk scan, in place (L -> S0), bf16 [j][i] -----
__global__ __launch_bounds__(256)
void k2_scan(unsigned short* __restrict__ L, const float* __restrict__ A)
{
    const int tid = blockIdx.x * 256 + threadIdx.x;   // (bh, j, i4), i fastest
    const int i4 = tid & 15;
    const int j  = (tid >> 4) & 63;
    const int bh = tid >> 10;

    const int lstride = N * N;               // elems per chunk tile
    int lidx = bh * NG * lstride + j * 64 + i4 * 4;
    int aidx = bh * NG * N + i4 * 4;

    float s0 = 0.f, s1 = 0.f, s2 = 0.f, s3 = 0.f;
    for (int g = 0; g < NG; ++g) {
        const uint2  lw = *(const uint2*)&L[lidx];
        const float4 a  = *(const float4*)&A[aidx];
        uint2 wsto;
        wsto.x = (unsigned)cv(s0) | ((unsigned)cv(s1) << 16);
        wsto.y = (unsigned)cv(s2) | ((unsigned)cv(s3) << 16);
        *(uint2*)&L[lidx] = wsto;            // state at START of chunk g
        s0 = fmaf(a.x, s0, bflo(lw.x));
        s1 = fmaf(a.y, s1, bfhi(lw.x));
        s2 = fmaf(a.z, s2, bflo(lw.y));
        s3 = fmaf(a.w, s3, bfhi(lw.y));
        lidx += lstride;
        aidx += N;
    }
}

// ---------------- no-workspace fallback: sequential per (b,h) ---------------
__global__ __launch_bounds__(64, 2)
void k_seq(const float* __restrict__ rp, const float* __restrict__ kp,
           const float* __restrict__ vp, const float* __restrict__ wp,
           const float* __restrict__ up, float* __restrict__ out)
{
    const int bh = blockIdx.x;
    const int b = bh / H, h = bh - b * H;
    const int j = threadIdx.x;

    float S[N];
#pragma unroll
    for (int i = 0; i < N; ++i) S[i] = 0.f;

    const int stride = H * N;
    int base = ((b * T) * H + h) * N;
    const int ubase = h * N;

#pragma unroll 1
    for (int tt = 0; tt < T; ++tt) {
        const float vj = vp[base + j];
        const int row = base;
        float sr = 0.f, o0 = 0.f, o1 = 0.f;
#pragma unroll
        for (int i = 0; i < N; ++i) {
            const float ki = kp[row + i];
            const float di = __expf(-__expf(wp[row + i]));
            const float ri = rp[row + i];
            sr = fmaf(ri * up[ubase + i], ki, sr);
            if (i & 1) o1 = fmaf(ri, S[i], o1);
            else       o0 = fmaf(ri, S[i], o0);
            S[i] = fmaf(di, S[i], ki * vj);
        }
        out[base + j] = fmaf(sr, vj, o0 + o1);
        base += stride;
    }
}

} // anon namespace

extern "C" void kernel_launch(void* const* d_in, const int* in_sizes, int n_in,
                              void* d_out, int out_size, void* d_ws, size_t ws_size,
                              hipStream_t stream)
{
    const float* r = (const float*)d_in[0];
    const float* k = (const float*)d_in[1];
    const float* v = (const float*)d_in[2];
    const float* w = (const float*)d_in[3];
    const float* u = (const float*)d_in[4];
    float* out = (float*)d_out;

    const size_t l_elems = (size_t)BH * NG * N * N;   // 8,388,608 bf16 (16.8MB)
    const size_t a_elems = (size_t)BH * NG * N;       // 131,072 fp32
    const size_t ws_need = l_elems * sizeof(unsigned short)
                         + a_elems * sizeof(float);   // ~17.3 MB

    if (ws_size >= ws_need) {
        unsigned short* L = (unsigned short*)d_ws;
        float* A = (float*)(L + l_elems);
        k13<0><<<BH * NG, 256, 0, stream>>>(r, k, v, w, u, nullptr, L, A, nullptr);
        k2_scan<<<(BH * N * 16) / 256, 256, 0, stream>>>(L, A);
        k13<1><<<BH * NG, 256, 0, stream>>>(r, k, v, w, u, L, nullptr, nullptr, out);
    } else {
        k_seq<<<BH, 64, 0, stream>>>(r, k, v, w, u, out);
    }
}

// Round 16
// 71.815 us; speedup vs baseline: 1.0746x; 1.0746x over previous
//
#include <hip/hip_runtime.h>
#include <math.h>

// RWKV-6 fused recurrent WKV — chunked linear scan, MFMA formulation.
// B=4, T=2048, H=16, N=64, fp32 in/out; bf16 MFMA operands, fp32 accum.
//
// Chunk TC=64 per workgroup (bh,g), 4 waves, wave w owns t-band [16w,16w+16).
// A[t,s] = sum_i r_t,i k_s,i exp(-(c[t-1]-c[s])), c = incl. prefix of exp(w).
// Dyadic-safe factorization (all staged exponents <= 0). Levels 0-3 + u-diag
// inside 16x16 diag tiles (masked accum); L4: tiles (1,0),(3,2); L5: (2,*),
// (3,0),(3,1). o = R~0 @ S0 + A @ V;  L_g = K~end^T @ V -> K2 scan.
//
// R8 lesson: never trade register live-range for LDS (accO stays last).
// R9 lesson: __float2bfloat16 tips regalloc into spill; manual RNE is stable.
// R10 lesson: phase-1 wall is the CU-shared LDS pipe + latency at low occ.
// R11-R14 lessons (NaN): (a) sST staged 8 of 16 cols -> uninit LDS into MFMA;
//   (b) union{s8v,u[4]} punning / cvt_pk asm combo NaN'd even with (a) fixed
//   -> both permanently excluded. Primitives restricted to the R10-proven set.
// R15 lesson: bf16-L halved bytes but the TRANSPOSED [j][i] layout made S0
//   reads 32B-per-lane gathers (+7us on P1). Layout must serve the consumer's
//   lane pattern: R16 returns L/S0 to row-major [i][j] (coalesced producer,
//   scan, and column-read staging), keeps bf16.
// R16 new: sST buffer eliminated — S0 staged into sB AFTER the L5 GEMM
//   (its last read), +2 barriers. LDS 37.9 -> 28.7KB => 5 blocks/CU.

namespace {
constexpr int B = 4, T = 2048, H = 16, N = 64;
constexpr int BH = B * H;
constexpr int NG = 32;           // chunks per (b,h)
constexpr int TC = 64;           // steps per chunk
constexpr int LDP = 72;          // LDS row stride (elems): 144B, 16B-aligned

typedef __attribute__((ext_vector_type(8))) short s8v;   // 8 bf16
typedef __attribute__((ext_vector_type(4))) float f4v;

#define MFMA16(a, b, c) __builtin_amdgcn_mfma_f32_16x16x32_bf16((a), (b), (c), 0, 0, 0)

__device__ __forceinline__ unsigned short cv(float f) {
    union { float f; unsigned u; } x; x.f = f;
    unsigned r = x.u + 0x7FFFu + ((x.u >> 16) & 1u);   // branchless RNE
    return (unsigned short)(r >> 16);
}

__device__ __forceinline__ float bfhi(unsigned u) {   // upper bf16 -> float
    union { unsigned u; float f; } x; x.u = u & 0xFFFF0000u; return x.f;
}
__device__ __forceinline__ float bflo(unsigned u) {   // lower bf16 -> float
    union { unsigned u; float f; } x; x.u = u << 16; return x.f;
}

// Padded element index: row*72 + col. Affine in row.
__device__ __forceinline__ int sw(int row, int col) {
    return row * LDP + col;
}

// MFMA fragment load: lane l -> row (l&15), k-slice 8*(l>>4); b128 read.
__device__ __forceinline__ s8v frag8(const unsigned short* buf, int row_base, int k_base) {
    const int l = threadIdx.x & 63;
    return *(const s8v*)&buf[sw(row_base + (l & 15), k_base + 8 * (l >> 4))];
}

// ---------------- K1/K3 merged: PHASE 0 = local states, PHASE 1 = outputs ---
// Lg/S0g: bf16, row-major [i][j] per chunk (64x64) — coalesced everywhere.
template<int PHASE>
__global__ __launch_bounds__(256, 4)
void k13(const float* __restrict__ rp, const float* __restrict__ kp,
         const float* __restrict__ vp, const float* __restrict__ wp,
         const float* __restrict__ up,
         const unsigned short* __restrict__ S0g,   // PHASE1: chunk-start states
         unsigned short* __restrict__ Lg, float* __restrict__ Ag,
         float* __restrict__ out)
{
    __shared__ unsigned short sA[64 * LDP];   // staging A-op; aliases sAm (late)
    __shared__ unsigned short sB[64 * LDP];   // staging B-op; aliases sST (late)
    __shared__ unsigned short sVT[64 * LDP];  // V transposed [j][t]
    __shared__ float spans[4 * 64];
    unsigned short* const sAm = sA;           // A-matrix bf16 [t][s] (late alias)
    unsigned short* const sST = sB;           // S0^T [j][i], staged after L5 GEMM

    const int blk = blockIdx.x;
    const int g   = blk & (NG - 1);
    const int bh  = blk / NG;
    const int b   = bh / H, h = bh - b * H;
    const int wv  = threadIdx.x >> 6;        // wave 0..3, owns t-band [16wv,+16)
    const int ln  = threadIdx.x & 63;        // lane: i (prep) / frag lane (GEMM)

    const int stride = H * N;
    const int base_w = ((b * T + g * TC + wv * 16) * H + h) * N + ln;
    const int cb = (bh * NG + g) * (N * N);

    // ---- P1: load rows, cum prefix, stage V^T ------------------------------
    float ci[16];                            // inclusive prefix of exp(w)
    float k_[16], r_[16];
    {
        float run = 0.f;
#pragma unroll
        for (int tt = 0; tt < 16; ++tt) {
            const int a = base_w + tt * stride;
            run += __expf(wp[a]);
            ci[tt] = run;
            k_[tt] = kp[a];
            if (PHASE == 1) r_[tt] = rp[a];
        }
        spans[wv * 64 + ln] = run;
    }
#pragma unroll
    for (int half = 0; half < 2; ++half) {   // V^T: row j=ln, cols t (own band)
        s8v pk;
#pragma unroll
        for (int e = 0; e < 8; ++e)
            pk[e] = (short)cv(vp[base_w + (half * 8 + e) * stride]);
        *(s8v*)&sVT[sw(ln, wv * 16 + half * 8)] = pk;
    }
    __syncthreads();
    const float sp0 = spans[0 * 64 + ln], sp1 = spans[1 * 64 + ln];
    const float sp2 = spans[2 * 64 + ln], sp3 = spans[3 * 64 + ln];
    const float offW = (wv > 0 ? sp0 : 0.f) + (wv > 1 ? sp1 : 0.f) + (wv > 2 ? sp2 : 0.f);
    const float ctot = sp0 + sp1 + sp2 + sp3;

    if (PHASE == 0) {
        // ---- K~end^T staging into sA as [i=ln][t] --------------------------
        s8v p0, p1;
#pragma unroll
        for (int tt = 0; tt < 16; ++tt) {
            const unsigned short v16 =
                cv(k_[tt] * __expf(-(ctot - (offW + ci[tt]))));
            if (tt < 8) p0[tt] = (short)v16; else p1[tt - 8] = (short)v16;
        }
        *(s8v*)&sA[sw(ln, wv * 16)]     = p0;
        *(s8v*)&sA[sw(ln, wv * 16 + 8)] = p1;
        __syncthreads();
        // ---- L[i][j] = sum_t KT[i][t] V[t][j]; wave owns i-band ------------
#pragma unroll
        for (int jb = 0; jb < 4; ++jb) {
            f4v acc = {0.f, 0.f, 0.f, 0.f};
            acc = MFMA16(frag8(sA, wv * 16, 0),  frag8(sVT, jb * 16, 0),  acc);
            acc = MFMA16(frag8(sA, wv * 16, 32), frag8(sVT, jb * 16, 32), acc);
            // acc[q] at (i = i0+q, j); row-major bf16 store, coalesced over ln&15
            const int i0 = wv * 16 + (ln >> 4) * 4;
            const int j  = jb * 16 + (ln & 15);
#pragma unroll
            for (int q = 0; q < 4; ++q)
                Lg[cb + (i0 + q) * 64 + j] = cv(acc[q]);
        }
        if (wv == 0) Ag[(bh * NG + g) * 64 + ln] = __expf(-ctot);
        return;
    }

    // ======================= PHASE 1: outputs ==============================
    const float uln = up[h * 64 + ln];
    const int cc = ln & 15;

    // ---- diag tile (wv,wv): shared plain-k B; level 0 + u-diag + levels 1-3
    f4v accD = {0.f, 0.f, 0.f, 0.f};
#pragma unroll
    for (int tt = 0; tt < 16; ++tt) sB[sw(wv * 16 + tt, ln)] = cv(k_[tt]);
    // level 0: scales identically 1 -> A = plain r
#pragma unroll
    for (int tt = 0; tt < 16; ++tt) sA[sw(wv * 16 + tt, ln)] = cv(r_[tt]);
    {
        f4v tmp = {0.f, 0.f, 0.f, 0.f};
        tmp = MFMA16(frag8(sA, wv * 16, 0),  frag8(sB, wv * 16, 0),  tmp);
        tmp = MFMA16(frag8(sA, wv * 16, 32), frag8(sB, wv * 16, 32), tmp);
#pragma unroll
        for (int q = 0; q < 4; ++q) {
            const int tt = (ln >> 4) * 4 + q;
            if (tt == cc + 1 && (tt & 1)) accD[q] += tmp[q];
        }
    }
    // u-diag: A = r*u, same plain-k B; mask t==s
#pragma unroll
    for (int tt = 0; tt < 16; ++tt) sA[sw(wv * 16 + tt, ln)] = cv(r_[tt] * uln);
    {
        f4v tmp = {0.f, 0.f, 0.f, 0.f};
        tmp = MFMA16(frag8(sA, wv * 16, 0),  frag8(sB, wv * 16, 0),  tmp);
        tmp = MFMA16(frag8(sA, wv * 16, 32), frag8(sB, wv * 16, 32), tmp);
#pragma unroll
        for (int q = 0; q < 4; ++q) {
            const int tt = (ln >> 4) * 4 + q;
            if (tt == cc) accD[q] += tmp[q];
        }
    }
    // levels 1..3: masked dyadic pairs
#pragma unroll
    for (int L = 1; L < 4; ++L) {
#pragma unroll
        for (int tt = 0; tt < 16; ++tt) {
            const int btl = (tt >> L) << L;          // floor boundary (local)
            const int bsl = btl + (1 << L);          // ceil boundary (local)
            const float cT  = (tt == 0) ? 0.f : ci[tt - 1];
            const float cBt = (btl == 0) ? 0.f : ci[btl - 1];
            const float cBs = ci[bsl - 1];
            sA[sw(wv * 16 + tt, ln)] = cv(r_[tt] * __expf(-(cT - cBt)));
            sB[sw(wv * 16 + tt, ln)] = cv(k_[tt] * __expf(-(cBs - ci[tt])));
        }
        f4v tmp = {0.f, 0.f, 0.f, 0.f};
        tmp = MFMA16(frag8(sA, wv * 16, 0),  frag8(sB, wv * 16, 0),  tmp);
        tmp = MFMA16(frag8(sA, wv * 16, 32), frag8(sB, wv * 16, 32), tmp);
#pragma unroll
        for (int q = 0; q < 4; ++q) {
            const int tt = (ln >> 4) * 4 + q;
            if (((tt >> L) == ((cc >> L) + 1)) && (((tt >> L) & 1) != 0))
                accD[q] += tmp[q];
        }
    }

    // ---- level 4: whole tiles (1,0),(3,2); refs = own band start/end -------
#pragma unroll
    for (int tt = 0; tt < 16; ++tt) {
        const float cT = (tt == 0) ? 0.f : ci[tt - 1];
        sA[sw(wv * 16 + tt, ln)] = cv(r_[tt] * __expf(-cT));
        sB[sw(wv * 16 + tt, ln)] = cv(k_[tt] * __expf(-(ci[15] - ci[tt])));
    }
    __syncthreads();
    f4v accL4 = {0.f, 0.f, 0.f, 0.f};
    if (wv == 1 || wv == 3) {
        accL4 = MFMA16(frag8(sA, wv * 16, 0),  frag8(sB, (wv - 1) * 16, 0),  accL4);
        accL4 = MFMA16(frag8(sA, wv * 16, 32), frag8(sB, (wv - 1) * 16, 32), accL4);
    }
    __syncthreads();   // cross-band sB reads done before L5 prep overwrites

    // ---- level 5: tiles (2,0),(2,1),(3,0),(3,1); refs at c[32] -------------
#pragma unroll
    for (int tt = 0; tt < 16; ++tt) {
        if (wv >= 2) {
            const float cT = (tt == 0) ? 0.f : ci[tt - 1];
            const float d  = (wv == 2) ? cT : (cT + sp2);
            sA[sw(wv * 16 + tt, ln)] = cv(r_[tt] * __expf(-d));
        } else {
            const float d = (wv == 0) ? (sp0 + sp1 - ci[tt]) : (sp1 - ci[tt]);
            sB[sw(wv * 16 + tt, ln)] = cv(k_[tt] * __expf(-d));
        }
    }
    __syncthreads();
    f4v acc50 = {0.f, 0.f, 0.f, 0.f}, acc51 = {0.f, 0.f, 0.f, 0.f};
    if (wv >= 2) {
        acc50 = MFMA16(frag8(sA, wv * 16, 0),  frag8(sB, 0, 0),   acc50);
        acc50 = MFMA16(frag8(sA, wv * 16, 32), frag8(sB, 0, 32),  acc50);
        acc51 = MFMA16(frag8(sA, wv * 16, 0),  frag8(sB, 16, 0),  acc51);
        acc51 = MFMA16(frag8(sA, wv * 16, 32), frag8(sB, 16, 32), acc51);
    }

    // ---- R~0 prep (own sA rows; own-row L5 reads done in-order) ------------
#pragma unroll
    for (int tt = 0; tt < 16; ++tt) {
        const float cT = (tt == 0) ? 0.f : ci[tt - 1];
        sA[sw(wv * 16 + tt, ln)] = cv(r_[tt] * __expf(-(offW + cT)));
    }
    __syncthreads();   // all waves' L5-GEMM reads of sB done -> sB reusable

    // ---- stage S0^T into sST(=sB): wave wv fills cols [wv*16,+16) of every
    //      row ln. S0 row-major [i][j] bf16 -> 16 coalesced ushort loads
    //      (lane=fast index), pure bit-placement (no conversion). ------------
    {
        s8v p0, p1;
#pragma unroll
        for (int e = 0; e < 8; ++e) {
            p0[e] = (short)S0g[cb + (wv * 16 + e) * 64 + ln];
            p1[e] = (short)S0g[cb + (wv * 16 + 8 + e) * 64 + ln];
        }
        *(s8v*)&sST[sw(ln, wv * 16)]     = p0;
        *(s8v*)&sST[sw(ln, wv * 16 + 8)] = p1;
    }
    __syncthreads();   // sST fully staged before cross-row reads

    // ---- O_inter = R~0 @ S0 (accO short-lived!) ----------------------------
    f4v accO[4];
#pragma unroll
    for (int jb = 0; jb < 4; ++jb) {
        f4v a = {0.f, 0.f, 0.f, 0.f};
        a = MFMA16(frag8(sA, wv * 16, 0),  frag8(sST, jb * 16, 0),  a);
        a = MFMA16(frag8(sA, wv * 16, 32), frag8(sST, jb * 16, 32), a);
        accO[jb] = a;
    }

    // ---- materialize A into sAm (=sA alias): own-band rows only, after the
    //      last own-row sA read (accO GEMM, wave-in-order) -> safe -----------
#pragma unroll
    for (int q = 0; q < 4; ++q) {
        const int tt = (ln >> 4) * 4 + q;
        sAm[sw(wv * 16 + tt, wv * 16 + cc)] = cv(accD[q]);
    }
    if (wv == 1 || wv == 3) {
#pragma unroll
        for (int q = 0; q < 4; ++q) {
            const int tt = (ln >> 4) * 4 + q;
            sAm[sw(wv * 16 + tt, (wv - 1) * 16 + cc)] = cv(accL4[q]);
        }
    }
    if (wv >= 2) {
#pragma unroll
        for (int q = 0; q < 4; ++q) {
            const int tt = (ln >> 4) * 4 + q;
            sAm[sw(wv * 16 + tt, cc)]      = cv(acc50[q]);
            sAm[sw(wv * 16 + tt, 16 + cc)] = cv(acc51[q]);
        }
    }
    if (wv == 0 || wv == 2) {    // zero upper-adjacent tile for K32 pairing
#pragma unroll
        for (int q = 0; q < 4; ++q) {
            const int tt = (ln >> 4) * 4 + q;
            sAm[sw(wv * 16 + tt, (wv + 1) * 16 + cc)] = 0;
        }
    }

    // ---- out = accO + A @ V (A-op: own rows; B-op: sVT stable since P1) ----
#pragma unroll
    for (int jb = 0; jb < 4; ++jb) {
        f4v a = accO[jb];
        a = MFMA16(frag8(sAm, wv * 16, 0), frag8(sVT, jb * 16, 0), a);
        if (wv >= 2)
            a = MFMA16(frag8(sAm, wv * 16, 32), frag8(sVT, jb * 16, 32), a);
#pragma unroll
        for (int q = 0; q < 4; ++q) {
            const int t = g * TC + wv * 16 + (ln >> 4) * 4 + q;
            out[((b * T + t) * H + h) * N + jb * 16 + (ln & 15)] = a[q];
        }
    }
}

// ---------------- K2: inter-chunk scan, in place (L -> S0), bf16 [i][j] -----
// Thread owns 2 consecutive j at fixed (bh,i): one uint load/store per chunk,
// j-fast thread mapping -> perfectly coalesced.
__global__ __launch_bounds__(256)
void k2_scan(unsigned short* __restrict__ L, const float* __restrict__ A)
{
    const int tid = blockIdx.x * 256 + threadIdx.x;   // (bh, i, j2), j2 fastest
    const int j2 = tid & 31;             // uint column (2 bf16)
    const int i  = (tid >> 5) & 63;
    const int bh = tid >> 11;

    unsigned* Lu = (unsigned*)L;
    const int lstride = N * N / 2;       // uints per chunk tile (2048)
    int lidx = (bh * NG) * lstride + i * 32 + j2;
    int aidx = (bh * NG) * N + i;

    float s0 = 0.f, s1 = 0.f;
    for (int g = 0; g < NG; ++g) {
        const unsigned lw = Lu[lidx];
        const float a = A[aidx];
        Lu[lidx] = (unsigned)cv(s0) | ((unsigned)cv(s1) << 16);  // chunk-start state
        s0 = fmaf(a, s0, bflo(lw));
        s1 = fmaf(a, s1, bfhi(lw));
        lidx += lstride;
        aidx += N;
    }
}

// ---------------- no-workspace fallback: sequential per (b,h) ---------------
__global__ __launch_bounds__(64, 2)
void k_seq(const float* __restrict__ rp, const float* __restrict__ kp,
           const float* __restrict__ vp, const float* __restrict__ wp,
           const float* __restrict__ up, float* __restrict__ out)
{
    const int bh = blockIdx.x;
    const int b = bh / H, h = bh - b * H;
    const int j = threadIdx.x;

    float S[N];
#pragma unroll
    for (int i = 0; i < N; ++i) S[i] = 0.f;

    const int stride = H * N;
    int base = ((b * T) * H + h) * N;
    const int ubase = h * N;

#pragma unroll 1
    for (int tt = 0; tt < T; ++tt) {
        const float vj = vp[base + j];
        const int row = base;
        float sr = 0.f, o0 = 0.f, o1 = 0.f;
#pragma unroll
        for (int i = 0; i < N; ++i) {
            const float ki = kp[row + i];
            const float di = __expf(-__expf(wp[row + i]));
            const float ri = rp[row + i];
            sr = fmaf(ri * up[ubase + i], ki, sr);
            if (i & 1) o1 = fmaf(ri, S[i], o1);
            else       o0 = fmaf(ri, S[i], o0);
            S[i] = fmaf(di, S[i], ki * vj);
        }
        out[base + j] = fmaf(sr, vj, o0 + o1);
        base += stride;
    }
}

} // anon namespace

extern "C" void kernel_launch(void* const* d_in, const int* in_sizes, int n_in,
                              void* d_out, int out_size, void* d_ws, size_t ws_size,
                              hipStream_t stream)
{
    const float* r = (const float*)d_in[0];
    const float* k = (const float*)d_in[1];
    const float* v = (const float*)d_in[2];
    const float* w = (const float*)d_in[3];
    const float* u = (const float*)d_in[4];
    float* out = (float*)d_out;

    const size_t l_elems = (size_t)BH * NG * N * N;   // 8,388,608 bf16 (16.8MB)
    const size_t a_elems = (size_t)BH * NG * N;       // 131,072 fp32
    const size_t ws_need = l_elems * sizeof(unsigned short)
                         + a_elems * sizeof(float);   // ~17.3 MB

    if (ws_size >= ws_need) {
        unsigned short* L = (unsigned short*)d_ws;
        float* A = (float*)(L + l_elems);
        k13<0><<<BH * NG, 256, 0, stream>>>(r, k, v, w, u, nullptr, L, A, nullptr);
        k2_scan<<<(BH * N * N / 2) / 256, 256, 0, stream>>>(L, A);
        k13<1><<<BH * NG, 256, 0, stream>>>(r, k, v, w, u, L, nullptr, nullptr, out);
    } else {
        k_seq<<<BH, 64, 0, stream>>>(r, k, v, w, u, out);
    }
}